// Round 15
// baseline (16.912 us; speedup 1.0000x reference)
//
#include <hip/hip_runtime.h>

#define NROWS 8192
#define NCLS  100
#define NB    (NROWS / 4)        // 2048 blocks
#define LN2   0.6931471805599453f
#define LOG2E 1.4426950408889634f

#if __has_builtin(__builtin_amdgcn_exp2f)
#define EXP2F(x) __builtin_amdgcn_exp2f(x)
#else
#define EXP2F(x) __expf((x) * LN2)
#endif
#if __has_builtin(__builtin_amdgcn_logf)
#define LOG2F(x) __builtin_amdgcn_logf(x)
#else
#define LOG2F(x) (__logf(x) * LOG2E)
#endif

// idx in [0,300) -> strict-upper-triangle 4x4 tile coords (I < J), J in [1,25)
#define TILEIJ(idx, I, J) \
    float s_##I = sqrtf(fmaf(8.f, (float)(idx), 1.f)); \
    int J = (int)((1.0f + s_##I) * 0.5f); \
    int I = (idx) - ((J * (J - 1)) >> 1);

// one pair term: P *= (Ea*Rb + Eb*Ra) = 2^-4*(2^(d/2)+2^(-d/2)); f(|d|)=2*log2(h)+8
#define HT(EA, RA, EB, RB, P) { P *= fmaf((EB), (RA), (EA) * (RB)); }

#define TILE16H(Ea, Ra, Eb, Rb, P0, P1, P2, P3) \
  HT(Ea.x, Ra.x, Eb.x, Rb.x, P0) HT(Ea.x, Ra.x, Eb.y, Rb.y, P0) \
  HT(Ea.x, Ra.x, Eb.z, Rb.z, P0) HT(Ea.x, Ra.x, Eb.w, Rb.w, P0) \
  HT(Ea.y, Ra.y, Eb.x, Rb.x, P1) HT(Ea.y, Ra.y, Eb.y, Rb.y, P1) \
  HT(Ea.y, Ra.y, Eb.z, Rb.z, P1) HT(Ea.y, Ra.y, Eb.w, Rb.w, P1) \
  HT(Ea.z, Ra.z, Eb.x, Rb.x, P2) HT(Ea.z, Ra.z, Eb.y, Rb.y, P2) \
  HT(Ea.z, Ra.z, Eb.z, Rb.z, P2) HT(Ea.z, Ra.z, Eb.w, Rb.w, P2) \
  HT(Ea.w, Ra.w, Eb.x, Rb.x, P3) HT(Ea.w, Ra.w, Eb.y, Rb.y, P3) \
  HT(Ea.w, Ra.w, Eb.z, Rb.z, P3) HT(Ea.w, Ra.w, Eb.w, Rb.w, P3)

// wave-64 sum via DPP (VALU pipe only, no LDS): result valid in lane 63
__device__ __forceinline__ float wave_dpp_sum(float v) {
#define DPPADD(ctrl) { int y_ = __builtin_amdgcn_update_dpp( \
        0, __builtin_bit_cast(int, v), (ctrl), 0xf, 0xf, true); \
        v += __builtin_bit_cast(float, y_); }
    DPPADD(0x111)   // row_shr:1
    DPPADD(0x112)   // row_shr:2
    DPPADD(0x114)   // row_shr:4
    DPPADD(0x118)   // row_shr:8  -> lane 15 of each row = row sum
    DPPADD(0x142)   // row_bcast15 -> lane 31 = rows0+1, lane 63 partial
    DPPADD(0x143)   // row_bcast31 -> lane 63 = total
#undef DPPADD
    return v;
}

__global__ __launch_bounds__(256, 8) void cpc_rows(const float* __restrict__ in,
                                                   const int* __restrict__ tgt,
                                                   float* __restrict__ qb) {
    __shared__ __align__(16) float sx[4][128], sE[4][128], sR[4][128];
    __shared__ float bred[4][3];

    const int tid = threadIdx.x;
    const int w   = tid >> 6;                    // wave = row-in-block
    const int l   = tid & 63;
    const int row = blockIdx.x * 4 + w;
    const float* x = in + row * NCLS;

    // ---- stage (x', E, R), log2 domain ----
    float x0 = x[l] * LOG2E;
    float E0 = EXP2F((x0 - 4.f) * 0.5f);
    sx[w][l] = x0;
    sE[w][l] = E0;
    sR[w][l] = EXP2F((x0 + 4.f) * -0.5f);
    const bool v1 = (l < NCLS - 64);             // lanes 0..35 hold a second class
    float x1 = 0.f, E1 = 0.f;
    if (v1) {
        x1 = x[64 + l] * LOG2E;
        E1 = EXP2F((x1 - 4.f) * 0.5f);
        sx[w][64 + l] = x1;
        sE[w][64 + l] = E1;
        sR[w][64 + l] = EXP2F((x1 + 4.f) * -0.5f);
    }
    // Each wave reads ONLY its own LDS slice [w][*]: wave-local DS-queue drain
    // suffices for cross-LANE visibility — no cross-wave barrier needed here.
    asm volatile("s_waitcnt lgkmcnt(0)" ::: "memory");

    const int   t  = tgt[row];
    const float xt = sx[w][t];

    // ---- singles: sumexp (via E^2), sum-x, target-pair stats ----
    float At, Pb, es, xs;
    {
        float a0 = fabsf(xt - x0);
        float e0 = (l == t) ? 0.f : EXP2F(-a0);
        At = a0; Pb = 1.f + e0;
        es = E0 * E0;                            // = 2^(x0-4)
        xs = x0;
    }
    {
        float a1 = v1 ? fabsf(xt - x1) : 0.f;
        float e1 = (v1 && (64 + l) != t) ? EXP2F(-a1) : 0.f;
        At += a1; Pb = fmaf(Pb, e1, Pb);
        es = v1 ? fmaf(E1, E1, es) : es;
        xs += x1;                                // x1 = 0 when !v1
    }
    float lPb = LOG2F(Pb);

    const float* pE = sE[w];
    const float* pR = sR[w];

    // ---- off-diagonal 4x4 tiles: 300 tiles; products of h, no trans in loop ----
    float P0 = 1.f, P1 = 1.f, P2 = 1.f, P3 = 1.f;
    float cst = 512.f;                           // 4 iters x 16 terms x 8
#pragma unroll 1
    for (int it = 0; it < 4; ++it) {
        int idx = it * 64 + l;
        TILEIJ(idx, I, J)
        float4 Ea = *(const float4*)(pE + 4 * I);
        float4 Ra = *(const float4*)(pR + 4 * I);
        float4 Eb = *(const float4*)(pE + 4 * J);
        float4 Rb = *(const float4*)(pR + 4 * J);
        TILE16H(Ea, Ra, Eb, Rb, P0, P1, P2, P3)
    }
    {   // tail: idx = 256 + l, valid < 300
        int idx = 256 + l;
        bool tv = idx < 300;
        int idxc = tv ? idx : 0;
        TILEIJ(idxc, I, J)
        float4 Ea = *(const float4*)(pE + 4 * I);
        float4 Ra = *(const float4*)(pR + 4 * I);
        float4 Eb = *(const float4*)(pE + 4 * J);
        float4 Rb = *(const float4*)(pR + 4 * J);
        float S0 = P0, S1 = P1, S2 = P2, S3 = P3;
        TILE16H(Ea, Ra, Eb, Rb, P0, P1, P2, P3)
        P0 = tv ? P0 : S0; P1 = tv ? P1 : S1;
        P2 = tv ? P2 : S2; P3 = tv ? P3 : S3;
        cst += tv ? 128.f : 0.f;
    }
    // ---- diagonal tiles: lane<25 -> tile (l,l); all 16 entries, halved in account ----
    float Pd0 = 1.f, Pd1 = 1.f;
    {
        bool dv = l < 25;
        int I = dv ? l : 0;
        float4 Ea = *(const float4*)(pE + 4 * I);
        float4 Ra = *(const float4*)(pR + 4 * I);
        TILE16H(Ea, Ra, Ea, Ra, Pd0, Pd1, Pd0, Pd1)
        Pd0 = dv ? Pd0 : 1.f;
        Pd1 = dv ? Pd1 : 1.f;
        cst += dv ? 64.f : 0.f;
    }

    // lS = sum of f over assigned pairs (+ halved selfs), log2 units
    float lS = 2.f * ((LOG2F(P0) + LOG2F(P1)) + (LOG2F(P2) + LOG2F(P3)))
             + LOG2F(Pd0 * Pd1) + cst;

    // ---- packed reduce: 3 values, DPP (VALU) — totals land in lane 63 ----
    float r0 = wave_dpp_sum(es);                 // -> sumexp * 2^-4
    float rU = wave_dpp_sum(xs + At + 2.f * lPb);            // -> q1
    float rW = wave_dpp_sum(At + 2.f * lPb - lS);            // -> q2

    if (l == 63) {
        bred[w][0] = LN2 * (LOG2F(r0) + 4.f - xt);     // CE
        bred[w][1] = LN2 * (50.f * xt - 0.5f * rU);    // sum logsig(xt - rest)
        bred[w][2] = LN2 * (rW + 1.f);                 // rest-pairs (+99*logsig(0))
    }
    __syncthreads();                             // bred IS cross-wave: keep this one
    if (tid < 3) {                               // 3 block-partials, SoA [3][NB]
        float s = bred[0][tid] + bred[1][tid] + bred[2][tid] + bred[3][tid];
        qb[tid * NB + blockIdx.x] = s;
    }
}

__global__ __launch_bounds__(256) void cpc_final(const float* __restrict__ qb,
                                                 float* __restrict__ out) {
    __shared__ double sred[4][3];
    const int tid = threadIdx.x;
    const int lane = tid & 63, wid = tid >> 6;
    double a0 = 0, a1 = 0, a2 = 0;
#pragma unroll
    for (int it = 0; it < 2; ++it) {             // 2 x 256 x 4 = 2048 per comp
        int idx = (it * 256 + tid) * 4;
        float4 v0 = *(const float4*)(qb + idx);
        float4 v1 = *(const float4*)(qb + NB + idx);
        float4 v2 = *(const float4*)(qb + 2 * NB + idx);
        a0 += (double)v0.x; a0 += (double)v0.y; a0 += (double)v0.z; a0 += (double)v0.w;
        a1 += (double)v1.x; a1 += (double)v1.y; a1 += (double)v1.z; a1 += (double)v1.w;
        a2 += (double)v2.x; a2 += (double)v2.y; a2 += (double)v2.z; a2 += (double)v2.w;
    }
#pragma unroll
    for (int off = 32; off; off >>= 1) {
        a0 += __shfl_xor(a0, off, 64);
        a1 += __shfl_xor(a1, off, 64);
        a2 += __shfl_xor(a2, off, 64);
    }
    if (lane == 0) { sred[wid][0] = a0; sred[wid][1] = a1; sred[wid][2] = a2; }
    __syncthreads();
    if (tid == 0) {
        double ce  = (sred[0][0] + sred[1][0] + sred[2][0] + sred[3][0]) / (double)NROWS;
        double bdc = -(sred[0][1] + sred[1][1] + sred[2][1] + sred[3][1])
                     / (double)(NCLS - 1) / (double)NROWS;
        double bec = -0.5 * (sred[0][2] + sred[1][2] + sred[2][2] + sred[3][2])
                     / (double)(NCLS - 1) / (double)(NCLS - 2) / (double)NROWS;
        out[0] = (float)(ce + bdc + bec);
        out[1] = (float)ce;
        out[2] = (float)bdc;
        out[3] = (float)bec;
    }
}

extern "C" void kernel_launch(void* const* d_in, const int* in_sizes, int n_in,
                              void* d_out, int out_size, void* d_ws, size_t ws_size,
                              hipStream_t stream) {
    const float* inputs  = (const float*)d_in[0];
    const int*   targets = (const int*)d_in[1];
    float*       out     = (float*)d_out;
    float*       qb      = (float*)d_ws;         // [3][2048] f32 = 24 KB

    cpc_rows<<<NB, 256, 0, stream>>>(inputs, targets, qb);
    cpc_final<<<1, 256, 0, stream>>>(qb, out);
}

// Round 16
// 14.754 us; speedup vs baseline: 1.1463x; 1.1463x over previous
//
#include <hip/hip_runtime.h>

#define NROWS 8192
#define NCLS  100
#define NBLK  (NROWS / 8)        // 1024 blocks, 8 rows/block (4 waves x 2 rows)
#define LN2   0.6931471805599453f
#define LOG2E 1.4426950408889634f

#if __has_builtin(__builtin_amdgcn_exp2f)
#define EXP2F(x) __builtin_amdgcn_exp2f(x)
#else
#define EXP2F(x) __expf((x) * LN2)
#endif
#if __has_builtin(__builtin_amdgcn_logf)
#define LOG2F(x) __builtin_amdgcn_logf(x)
#else
#define LOG2F(x) (__logf(x) * LOG2E)
#endif

// idx in [0,300) -> strict-upper-triangle 4x4 tile coords (I < J), J in [1,25)
#define TILEIJ(idx, I, J) \
    float s_##I = sqrtf(fmaf(8.f, (float)(idx), 1.f)); \
    int J = (int)((1.0f + s_##I) * 0.5f); \
    int I = (idx) - ((J * (J - 1)) >> 1);

// one pair term: P *= (Ea*Rb + Eb*Ra) = 2^-4*(2^(d/2)+2^(-d/2)); f(|d|)=2*log2(h)+8
#define HT(EA, RA, EB, RB, P) { P *= fmaf((EB), (RA), (EA) * (RB)); }

#define TILE16H(Ea, Ra, Eb, Rb, P0, P1, P2, P3) \
  HT(Ea.x, Ra.x, Eb.x, Rb.x, P0) HT(Ea.x, Ra.x, Eb.y, Rb.y, P0) \
  HT(Ea.x, Ra.x, Eb.z, Rb.z, P0) HT(Ea.x, Ra.x, Eb.w, Rb.w, P0) \
  HT(Ea.y, Ra.y, Eb.x, Rb.x, P1) HT(Ea.y, Ra.y, Eb.y, Rb.y, P1) \
  HT(Ea.y, Ra.y, Eb.z, Rb.z, P1) HT(Ea.y, Ra.y, Eb.w, Rb.w, P1) \
  HT(Ea.z, Ra.z, Eb.x, Rb.x, P2) HT(Ea.z, Ra.z, Eb.y, Rb.y, P2) \
  HT(Ea.z, Ra.z, Eb.z, Rb.z, P2) HT(Ea.z, Ra.z, Eb.w, Rb.w, P2) \
  HT(Ea.w, Ra.w, Eb.x, Rb.x, P3) HT(Ea.w, Ra.w, Eb.y, Rb.y, P3) \
  HT(Ea.w, Ra.w, Eb.z, Rb.z, P3) HT(Ea.w, Ra.w, Eb.w, Rb.w, P3)

// wave-64 sum via DPP (VALU pipe only, no LDS): result valid in lane 63
__device__ __forceinline__ float wave_dpp_sum(float v) {
#define DPPADD(ctrl) { int y_ = __builtin_amdgcn_update_dpp( \
        0, __builtin_bit_cast(int, v), (ctrl), 0xf, 0xf, true); \
        v += __builtin_bit_cast(float, y_); }
    DPPADD(0x111)   // row_shr:1
    DPPADD(0x112)   // row_shr:2
    DPPADD(0x114)   // row_shr:4
    DPPADD(0x118)   // row_shr:8  -> lane 15 of each row = row sum
    DPPADD(0x142)   // row_bcast15
    DPPADD(0x143)   // row_bcast31 -> lane 63 = total
#undef DPPADD
    return v;
}

// exponent/mantissa split: P = 2^(expo-127) * man, man in [1,2)
#define EXPSPLIT(P, EI, MF) \
    int   EI = __builtin_bit_cast(int, P) >> 23; \
    float MF = __builtin_bit_cast(float, (__builtin_bit_cast(int, P) & 0x007FFFFF) | 0x3F800000);

__global__ __launch_bounds__(256, 8) void cpc_rows(const float* __restrict__ in,
                                                   const int* __restrict__ tgt,
                                                   float* __restrict__ qb) {
    __shared__ __align__(16) float sx[4][2][128], sE[4][2][128], sR[4][2][128];  // 12 KB
    __shared__ float bred[4][3];

    const int tid = threadIdx.x;
    const int w   = tid >> 6;                    // wave
    const int l   = tid & 63;
    const int row0 = blockIdx.x * 8 + w * 2;     // 2 rows per wave
    const float* xA = in + row0 * NCLS;
    const float* xB = xA + NCLS;
    const bool v1 = (l < NCLS - 64);             // lanes 0..35 hold a second class

    // ---- stage BOTH rows (loads issue together; one exposed latency) ----
    float xa0 = xA[l] * LOG2E;
    float xb0 = xB[l] * LOG2E;
    float Ea0 = EXP2F((xa0 - 4.f) * 0.5f);
    float Eb0 = EXP2F((xb0 - 4.f) * 0.5f);
    sx[w][0][l] = xa0; sE[w][0][l] = Ea0; sR[w][0][l] = EXP2F((xa0 + 4.f) * -0.5f);
    sx[w][1][l] = xb0; sE[w][1][l] = Eb0; sR[w][1][l] = EXP2F((xb0 + 4.f) * -0.5f);
    float xa1 = 0.f, xb1 = 0.f, Ea1 = 0.f, Eb1 = 0.f;
    if (v1) {
        xa1 = xA[64 + l] * LOG2E;
        xb1 = xB[64 + l] * LOG2E;
        Ea1 = EXP2F((xa1 - 4.f) * 0.5f);
        Eb1 = EXP2F((xb1 - 4.f) * 0.5f);
        sx[w][0][64 + l] = xa1; sE[w][0][64 + l] = Ea1; sR[w][0][64 + l] = EXP2F((xa1 + 4.f) * -0.5f);
        sx[w][1][64 + l] = xb1; sE[w][1][64 + l] = Eb1; sR[w][1][64 + l] = EXP2F((xb1 + 4.f) * -0.5f);
    }
    const int t0 = tgt[row0];
    const int t1 = tgt[row0 + 1];
    __syncthreads();

    float acc0 = 0.f, acc1 = 0.f, acc2 = 0.f;    // per-wave (2-row) sums, valid lane 63

#pragma unroll 1
    for (int r = 0; r < 2; ++r) {
        const float* px = sx[w][r];
        const float* pE = sE[w][r];
        const float* pR = sR[w][r];
        const float x0 = r ? xb0 : xa0;
        const float x1 = r ? xb1 : xa1;
        const float E0 = r ? Eb0 : Ea0;
        const float E1 = r ? Eb1 : Ea1;
        const int   t  = r ? t1 : t0;
        const float xt = px[t];

        // ---- singles: sumexp (via E^2), sum-x, target-pair stats ----
        float At, Pb, es, xs;
        {
            float a0 = fabsf(xt - x0);
            float e0 = (l == t) ? 0.f : EXP2F(-a0);
            At = a0; Pb = 1.f + e0;
            es = E0 * E0;                        // = 2^(x0-4)
            xs = x0;
        }
        {
            float a1 = v1 ? fabsf(xt - x1) : 0.f;
            float e1 = (v1 && (64 + l) != t) ? EXP2F(-a1) : 0.f;
            At += a1; Pb = fmaf(Pb, e1, Pb);
            es = v1 ? fmaf(E1, E1, es) : es;
            xs += x1;                            // x1 = 0 when !v1
        }
        float lPb = LOG2F(Pb);

        // ---- off-diagonal 4x4 tiles: 300 tiles ----
        float P0 = 1.f, P1 = 1.f, P2 = 1.f, P3 = 1.f;
        float cst = 512.f;                       // 4 iters x 16 terms x 8
#pragma unroll 1
        for (int it = 0; it < 4; ++it) {
            int idx = it * 64 + l;
            TILEIJ(idx, I, J)
            float4 Ea = *(const float4*)(pE + 4 * I);
            float4 Ra = *(const float4*)(pR + 4 * I);
            float4 Eb = *(const float4*)(pE + 4 * J);
            float4 Rb = *(const float4*)(pR + 4 * J);
            TILE16H(Ea, Ra, Eb, Rb, P0, P1, P2, P3)
        }
        {   // tail: idx = 256 + l, valid < 300
            int idx = 256 + l;
            bool tv = idx < 300;
            int idxc = tv ? idx : 0;
            TILEIJ(idxc, I, J)
            float4 Ea = *(const float4*)(pE + 4 * I);
            float4 Ra = *(const float4*)(pR + 4 * I);
            float4 Eb = *(const float4*)(pE + 4 * J);
            float4 Rb = *(const float4*)(pR + 4 * J);
            float S0 = P0, S1 = P1, S2 = P2, S3 = P3;
            TILE16H(Ea, Ra, Eb, Rb, P0, P1, P2, P3)
            P0 = tv ? P0 : S0; P1 = tv ? P1 : S1;
            P2 = tv ? P2 : S2; P3 = tv ? P3 : S3;
            cst += tv ? 128.f : 0.f;
        }
        // ---- diagonal tiles: lane<25 -> tile (l,l) ----
        float Pd0 = 1.f, Pd1 = 1.f;
        {
            bool dv = l < 25;
            int I = dv ? l : 0;
            float4 Ea = *(const float4*)(pE + 4 * I);
            float4 Ra = *(const float4*)(pR + 4 * I);
            TILE16H(Ea, Ra, Ea, Ra, Pd0, Pd1, Pd0, Pd1)
            Pd0 = dv ? Pd0 : 1.f;
            Pd1 = dv ? Pd1 : 1.f;
            cst += dv ? 64.f : 0.f;
        }

        // ---- lS via exponent extraction: ONE log instead of five ----
        // lS = 2*sum(log2 Pk) + log2(Pd0*Pd1) + cst
        float Pd = Pd0 * Pd1;                    // in [2^-48, 2^40], safe
        EXPSPLIT(P0, e0i, m0) EXPSPLIT(P1, e1i, m1)
        EXPSPLIT(P2, e2i, m2) EXPSPLIT(P3, e3i, m3)
        EXPSPLIT(Pd, edi, md)
        int eAll = 2 * (((e0i + e1i) + (e2i + e3i)) - 508) + (edi - 127);
        float mA = (m0 * m1) * (m2 * m3);        // [1,256) after square: merged below
        float lS = (float)eAll + LOG2F((mA * mA) * md) + cst;   // mA^2*md in [1,512)

        // ---- packed reduce: 3 values, DPP — totals land in lane 63 ----
        float r0 = wave_dpp_sum(es);             // -> sumexp * 2^-4
        float rU = wave_dpp_sum(xs + At + 2.f * lPb);
        float rW = wave_dpp_sum(At + 2.f * lPb - lS);

        if (l == 63) {
            acc0 += LN2 * (LOG2F(r0) + 4.f - xt);      // CE
            acc1 += LN2 * (50.f * xt - 0.5f * rU);     // sum logsig(xt - rest)
            acc2 += LN2 * (rW + 1.f);                  // rest-pairs (+99*logsig(0))
        }
    }

    if (l == 63) { bred[w][0] = acc0; bred[w][1] = acc1; bred[w][2] = acc2; }
    __syncthreads();
    if (tid < 3) {                               // 3 block-partials, SoA [3][NBLK]
        float s = bred[0][tid] + bred[1][tid] + bred[2][tid] + bred[3][tid];
        qb[tid * NBLK + blockIdx.x] = s;
    }
}

__global__ __launch_bounds__(256) void cpc_final(const float* __restrict__ qb,
                                                 float* __restrict__ out) {
    __shared__ double sred[4][3];
    const int tid = threadIdx.x;
    const int lane = tid & 63, wid = tid >> 6;
    double a0 = 0, a1 = 0, a2 = 0;
    {                                            // 256 threads x 4 = 1024 per comp
        int idx = tid * 4;
        float4 v0 = *(const float4*)(qb + idx);
        float4 v1 = *(const float4*)(qb + NBLK + idx);
        float4 v2 = *(const float4*)(qb + 2 * NBLK + idx);
        a0 += (double)v0.x; a0 += (double)v0.y; a0 += (double)v0.z; a0 += (double)v0.w;
        a1 += (double)v1.x; a1 += (double)v1.y; a1 += (double)v1.z; a1 += (double)v1.w;
        a2 += (double)v2.x; a2 += (double)v2.y; a2 += (double)v2.z; a2 += (double)v2.w;
    }
#pragma unroll
    for (int off = 32; off; off >>= 1) {
        a0 += __shfl_xor(a0, off, 64);
        a1 += __shfl_xor(a1, off, 64);
        a2 += __shfl_xor(a2, off, 64);
    }
    if (lane == 0) { sred[wid][0] = a0; sred[wid][1] = a1; sred[wid][2] = a2; }
    __syncthreads();
    if (tid == 0) {
        double ce  = (sred[0][0] + sred[1][0] + sred[2][0] + sred[3][0]) / (double)NROWS;
        double bdc = -(sred[0][1] + sred[1][1] + sred[2][1] + sred[3][1])
                     / (double)(NCLS - 1) / (double)NROWS;
        double bec = -0.5 * (sred[0][2] + sred[1][2] + sred[2][2] + sred[3][2])
                     / (double)(NCLS - 1) / (double)(NCLS - 2) / (double)NROWS;
        out[0] = (float)(ce + bdc + bec);
        out[1] = (float)ce;
        out[2] = (float)bdc;
        out[3] = (float)bec;
    }
}

extern "C" void kernel_launch(void* const* d_in, const int* in_sizes, int n_in,
                              void* d_out, int out_size, void* d_ws, size_t ws_size,
                              hipStream_t stream) {
    const float* inputs  = (const float*)d_in[0];
    const int*   targets = (const int*)d_in[1];
    float*       out     = (float*)d_out;
    float*       qb      = (float*)d_ws;         // [3][1024] f32 = 12 KB

    cpc_rows<<<NBLK, 256, 0, stream>>>(inputs, targets, qb);
    cpc_final<<<1, 256, 0, stream>>>(qb, out);
}

// Round 17
// 14.640 us; speedup vs baseline: 1.1552x; 1.0078x over previous
//
#include <hip/hip_runtime.h>

#define NROWS 8192
#define NCLS  100
#define NB    (NROWS / 4)        // 2048 blocks
#define LN2   0.6931471805599453f
#define LOG2E 1.4426950408889634f

#if __has_builtin(__builtin_amdgcn_exp2f)
#define EXP2F(x) __builtin_amdgcn_exp2f(x)
#else
#define EXP2F(x) __expf((x) * LN2)
#endif
#if __has_builtin(__builtin_amdgcn_logf)
#define LOG2F(x) __builtin_amdgcn_logf(x)
#else
#define LOG2F(x) (__logf(x) * LOG2E)
#endif

// idx in [0,300) -> strict-upper-triangle 4x4 tile coords (I < J), J in [1,25)
#define TILEIJ(idx, I, J) \
    float s_##I = sqrtf(fmaf(8.f, (float)(idx), 1.f)); \
    int J = (int)((1.0f + s_##I) * 0.5f); \
    int I = (idx) - ((J * (J - 1)) >> 1);

// one pair term: P *= (Ea*Rb + Eb*Ra) = 2^-4*(2^(d/2)+2^(-d/2)); f(|d|)=2*log2(h)+8
#define HT(EA, RA, EB, RB, P) { P *= fmaf((EB), (RA), (EA) * (RB)); }

#define TILE16H(Ea, Ra, Eb, Rb, P0, P1, P2, P3) \
  HT(Ea.x, Ra.x, Eb.x, Rb.x, P0) HT(Ea.x, Ra.x, Eb.y, Rb.y, P0) \
  HT(Ea.x, Ra.x, Eb.z, Rb.z, P0) HT(Ea.x, Ra.x, Eb.w, Rb.w, P0) \
  HT(Ea.y, Ra.y, Eb.x, Rb.x, P1) HT(Ea.y, Ra.y, Eb.y, Rb.y, P1) \
  HT(Ea.y, Ra.y, Eb.z, Rb.z, P1) HT(Ea.y, Ra.y, Eb.w, Rb.w, P1) \
  HT(Ea.z, Ra.z, Eb.x, Rb.x, P2) HT(Ea.z, Ra.z, Eb.y, Rb.y, P2) \
  HT(Ea.z, Ra.z, Eb.z, Rb.z, P2) HT(Ea.z, Ra.z, Eb.w, Rb.w, P2) \
  HT(Ea.w, Ra.w, Eb.x, Rb.x, P3) HT(Ea.w, Ra.w, Eb.y, Rb.y, P3) \
  HT(Ea.w, Ra.w, Eb.z, Rb.z, P3) HT(Ea.w, Ra.w, Eb.w, Rb.w, P3)

// wave-64 sum via DPP (VALU pipe only, no LDS): result valid in lane 63
__device__ __forceinline__ float wave_dpp_sum(float v) {
#define DPPADD(ctrl) { int y_ = __builtin_amdgcn_update_dpp( \
        0, __builtin_bit_cast(int, v), (ctrl), 0xf, 0xf, true); \
        v += __builtin_bit_cast(float, y_); }
    DPPADD(0x111)   // row_shr:1
    DPPADD(0x112)   // row_shr:2
    DPPADD(0x114)   // row_shr:4
    DPPADD(0x118)   // row_shr:8  -> lane 15 of each row = row sum
    DPPADD(0x142)   // row_bcast15 -> lane 31 = rows0+1, lane 63 partial
    DPPADD(0x143)   // row_bcast31 -> lane 63 = total
#undef DPPADD
    return v;
}

__global__ __launch_bounds__(256, 8) void cpc_rows(const float* __restrict__ in,
                                                   const int* __restrict__ tgt,
                                                   float* __restrict__ qb) {
    __shared__ __align__(16) float sx[4][128], sE[4][128], sR[4][128];
    __shared__ float bred[4][3];

    const int tid = threadIdx.x;
    const int w   = tid >> 6;                    // wave = row-in-block
    const int l   = tid & 63;
    const int row = blockIdx.x * 4 + w;
    const float* x = in + row * NCLS;

    // ---- stage (x', E, R), log2 domain ----
    float x0 = x[l] * LOG2E;
    float E0 = EXP2F((x0 - 4.f) * 0.5f);
    sx[w][l] = x0;
    sE[w][l] = E0;
    sR[w][l] = EXP2F((x0 + 4.f) * -0.5f);
    const bool v1 = (l < NCLS - 64);             // lanes 0..35 hold a second class
    float x1 = 0.f, E1 = 0.f;
    if (v1) {
        x1 = x[64 + l] * LOG2E;
        E1 = EXP2F((x1 - 4.f) * 0.5f);
        sx[w][64 + l] = x1;
        sE[w][64 + l] = E1;
        sR[w][64 + l] = EXP2F((x1 + 4.f) * -0.5f);
    }
    __syncthreads();

    const int   t  = tgt[row];
    const float xt = sx[w][t];

    // ---- singles: sumexp (via E^2), sum-x, target-pair stats ----
    float At, Pb, es, xs;
    {
        float a0 = fabsf(xt - x0);
        float e0 = (l == t) ? 0.f : EXP2F(-a0);
        At = a0; Pb = 1.f + e0;
        es = E0 * E0;                            // = 2^(x0-4)
        xs = x0;
    }
    {
        float a1 = v1 ? fabsf(xt - x1) : 0.f;
        float e1 = (v1 && (64 + l) != t) ? EXP2F(-a1) : 0.f;
        At += a1; Pb = fmaf(Pb, e1, Pb);
        es = v1 ? fmaf(E1, E1, es) : es;
        xs += x1;                                // x1 = 0 when !v1
    }
    float lPb = LOG2F(Pb);

    const float* pE = sE[w];
    const float* pR = sR[w];

    // ---- off-diagonal 4x4 tiles: 300 tiles; products of h, no trans in loop ----
    float P0 = 1.f, P1 = 1.f, P2 = 1.f, P3 = 1.f;
    float cst = 512.f;                           // 4 iters x 16 terms x 8
#pragma unroll 1
    for (int it = 0; it < 4; ++it) {
        int idx = it * 64 + l;
        TILEIJ(idx, I, J)
        float4 Ea = *(const float4*)(pE + 4 * I);
        float4 Ra = *(const float4*)(pR + 4 * I);
        float4 Eb = *(const float4*)(pE + 4 * J);
        float4 Rb = *(const float4*)(pR + 4 * J);
        TILE16H(Ea, Ra, Eb, Rb, P0, P1, P2, P3)
    }
    {   // tail: idx = 256 + l, valid < 300
        int idx = 256 + l;
        bool tv = idx < 300;
        int idxc = tv ? idx : 0;
        TILEIJ(idxc, I, J)
        float4 Ea = *(const float4*)(pE + 4 * I);
        float4 Ra = *(const float4*)(pR + 4 * I);
        float4 Eb = *(const float4*)(pE + 4 * J);
        float4 Rb = *(const float4*)(pR + 4 * J);
        float S0 = P0, S1 = P1, S2 = P2, S3 = P3;
        TILE16H(Ea, Ra, Eb, Rb, P0, P1, P2, P3)
        P0 = tv ? P0 : S0; P1 = tv ? P1 : S1;
        P2 = tv ? P2 : S2; P3 = tv ? P3 : S3;
        cst += tv ? 128.f : 0.f;
    }
    // ---- diagonal tiles: lane<25 -> tile (l,l); all 16 entries, halved in account ----
    float Pd0 = 1.f, Pd1 = 1.f;
    {
        bool dv = l < 25;
        int I = dv ? l : 0;
        float4 Ea = *(const float4*)(pE + 4 * I);
        float4 Ra = *(const float4*)(pR + 4 * I);
        TILE16H(Ea, Ra, Ea, Ra, Pd0, Pd1, Pd0, Pd1)
        Pd0 = dv ? Pd0 : 1.f;
        Pd1 = dv ? Pd1 : 1.f;
        cst += dv ? 64.f : 0.f;
    }

    // lS = sum of f over assigned pairs (+ halved selfs), log2 units
    float lS = 2.f * ((LOG2F(P0) + LOG2F(P1)) + (LOG2F(P2) + LOG2F(P3)))
             + LOG2F(Pd0 * Pd1) + cst;

    // ---- packed reduce: 3 values, DPP (VALU) — totals land in lane 63 ----
    float r0 = wave_dpp_sum(es);                 // -> sumexp * 2^-4
    float rU = wave_dpp_sum(xs + At + 2.f * lPb);            // -> q1
    float rW = wave_dpp_sum(At + 2.f * lPb - lS);            // -> q2

    if (l == 63) {
        bred[w][0] = LN2 * (LOG2F(r0) + 4.f - xt);     // CE
        bred[w][1] = LN2 * (50.f * xt - 0.5f * rU);    // sum logsig(xt - rest)
        bred[w][2] = LN2 * (rW + 1.f);                 // rest-pairs (+99*logsig(0))
    }
    __syncthreads();
    if (tid < 3) {                               // 3 block-partials, SoA [3][NB]
        float s = bred[0][tid] + bred[1][tid] + bred[2][tid] + bred[3][tid];
        qb[tid * NB + blockIdx.x] = s;
    }
}

__global__ __launch_bounds__(256) void cpc_final(const float* __restrict__ qb,
                                                 float* __restrict__ out) {
    __shared__ double sred[4][3];
    const int tid = threadIdx.x;
    const int lane = tid & 63, wid = tid >> 6;
    double a0 = 0, a1 = 0, a2 = 0;
#pragma unroll
    for (int it = 0; it < 2; ++it) {             // 2 x 256 x 4 = 2048 per comp
        int idx = (it * 256 + tid) * 4;
        float4 v0 = *(const float4*)(qb + idx);
        float4 v1 = *(const float4*)(qb + NB + idx);
        float4 v2 = *(const float4*)(qb + 2 * NB + idx);
        a0 += (double)v0.x; a0 += (double)v0.y; a0 += (double)v0.z; a0 += (double)v0.w;
        a1 += (double)v1.x; a1 += (double)v1.y; a1 += (double)v1.z; a1 += (double)v1.w;
        a2 += (double)v2.x; a2 += (double)v2.y; a2 += (double)v2.z; a2 += (double)v2.w;
    }
#pragma unroll
    for (int off = 32; off; off >>= 1) {
        a0 += __shfl_xor(a0, off, 64);
        a1 += __shfl_xor(a1, off, 64);
        a2 += __shfl_xor(a2, off, 64);
    }
    if (lane == 0) { sred[wid][0] = a0; sred[wid][1] = a1; sred[wid][2] = a2; }
    __syncthreads();
    if (tid == 0) {
        double ce  = (sred[0][0] + sred[1][0] + sred[2][0] + sred[3][0]) / (double)NROWS;
        double bdc = -(sred[0][1] + sred[1][1] + sred[2][1] + sred[3][1])
                     / (double)(NCLS - 1) / (double)NROWS;
        double bec = -0.5 * (sred[0][2] + sred[1][2] + sred[2][2] + sred[3][2])
                     / (double)(NCLS - 1) / (double)(NCLS - 2) / (double)NROWS;
        out[0] = (float)(ce + bdc + bec);
        out[1] = (float)ce;
        out[2] = (float)bdc;
        out[3] = (float)bec;
    }
}

extern "C" void kernel_launch(void* const* d_in, const int* in_sizes, int n_in,
                              void* d_out, int out_size, void* d_ws, size_t ws_size,
                              hipStream_t stream) {
    const float* inputs  = (const float*)d_in[0];
    const int*   targets = (const int*)d_in[1];
    float*       out     = (float*)d_out;
    float*       qb      = (float*)d_ws;         // [3][2048] f32 = 24 KB

    cpc_rows<<<NB, 256, 0, stream>>>(inputs, targets, qb);
    cpc_final<<<1, 256, 0, stream>>>(qb, out);
}